// Round 3
// baseline (680.682 us; speedup 1.0000x reference)
//
#include <hip/hip_runtime.h>
#include <utility>

// ---- static problem structure -------------------------------------------
// Inputs (dict order!): A0, B0, A1, B1, A2, B2, A3, B3 : [4096, 2l+1, 16] f32.
// Packed per-batch layout (256 floats): row offsets loff = {0,16,64,144},
// element (l, m_i, p) at loff[l] + m_i*16 + p.  Packed row r = loff/16 + m_i:
// r=0 -> l=0; r=1..3 -> l=1; r=4..8 -> l=2; r=9..15 -> l=3.
// Output per batch: for l=0..3, for M, for pair (l1,l2) valid, 256-elt tile
// (p*16+q). Tile base = base[l] + (M*npairs[l] + pair)*256.
// base = {0,1024,7936,22016}, npairs = {4,9,11,10}. Total 39936 f32/batch.
#define NTILES 156
#define NTERMS 478
#define PB_OUT 39936

// ---- compile-time Clebsch-Gordan table ----------------------------------
constexpr double cfact(int n){ double f=1.0; for(int i=2;i<=n;++i) f*=(double)i; return f; }

constexpr double csqrt(double x){
  double g = (x > 1.0) ? x : 1.0;
  for (int i = 0; i < 32; ++i) g = 0.5*(g + x/g);
  return g;
}

constexpr double cg_coef(int j1,int m1,int j2,int m2,int j,int m){
  if (m1+m2 != m) return 0.0;
  double pref = csqrt((2.0*j+1.0)*cfact(j+j1-j2)*cfact(j-j1+j2)*cfact(j1+j2-j)/cfact(j1+j2+j+1));
  pref *= csqrt(cfact(j+m)*cfact(j-m)*cfact(j1+m1)*cfact(j1-m1)*cfact(j2+m2)*cfact(j2-m2));
  double s = 0.0;
  for (int k = 0; k <= j1+j2-j; ++k){
    int d2=j1+j2-j-k, d3=j1-m1-k, d4=j2+m2-k, d5=j-j2+m1+k, d6=j-j1-m2+k;
    if (d2<0||d3<0||d4<0||d5<0||d6<0) continue;
    double denom = cfact(k)*cfact(d2)*cfact(d3)*cfact(d4)*cfact(d5)*cfact(d6);
    s += ((k&1) ? -1.0 : 1.0)/denom;
  }
  return pref*s;
}

struct Tables {
  int   tiles[NTILES];   // out_off | (term_start<<16) | (count<<26)
  int   tpack[NTERMS];   // a_off | (b_off<<8)   (offsets into packed 256-f layout)
  float tcg[NTERMS];     // CG coefficient
};

constexpr Tables build_tables(){
  Tables t{};
  const int loff[4]   = {0,16,64,144};
  const int base[4]   = {0,1024,7936,22016};
  const int npairs[4] = {4,9,11,10};
  int tile_i = 0, term_i = 0;
  for (int l = 0; l <= 3; ++l){
    int pair_i = 0;
    for (int l1 = 0; l1 <= 3; ++l1){
      for (int l2 = 0; l2 <= 3; ++l2){
        int dl = l1 - l2; if (dl < 0) dl = -dl;
        if (!(dl <= l && l <= l1 + l2)) continue;
        for (int Mi = 0; Mi < 2*l + 1; ++Mi){
          int M = Mi - l;
          int m1lo = (-l1 > M - l2) ? -l1 : M - l2;
          int m1hi = ( l1 < M + l2) ?  l1 : M + l2;
          int cnt  = m1hi - m1lo + 1;
          int ooff = base[l] + (Mi*npairs[l] + pair_i)*256;
          t.tiles[tile_i] = ooff | (term_i << 16) | (cnt << 26);
          for (int m1 = m1lo; m1 <= m1hi; ++m1){
            int m2 = M - m1;
            t.tpack[term_i] = (loff[l1] + (m1 + l1)*16) | ((loff[l2] + (m2 + l2)*16) << 8);
            t.tcg[term_i]   = (float)cg_coef(l1, m1, l2, m2, l, M);
            ++term_i;
          }
          ++tile_i;
        }
        ++pair_i;
      }
    }
  }
  return t;
}

static constexpr Tables k_tab = build_tables();

// ---- compile-time unroll helper ------------------------------------------
template <class F, int... Is>
__device__ __forceinline__ void static_for_impl(F&& f, std::integer_sequence<int, Is...>){
  ( f(std::integral_constant<int, Is>{}), ... );
}
template <int N, class F>
__device__ __forceinline__ void static_for(F&& f){
  static_for_impl(f, std::make_integer_sequence<int, N>{});
}

// ---- main kernel ---------------------------------------------------------
// One WAVE per batch element (4 waves/block -> 4 batch elems/block).
// Each thread owns (p, q0..q0+3): preload A-column (16 regs) + B-quad
// (16 x float4 regs) from global, then a fully static unrolled stream of
// 478 terms (CG coefs as literals, register operands only) and 156
// coalesced 1KB/wave float4 stores. No LDS, no barriers, no s_loads in loop.
__global__ __launch_bounds__(256, 4) void cg_main(
    const float* __restrict__ A0, const float* __restrict__ A1,
    const float* __restrict__ A2, const float* __restrict__ A3,
    const float* __restrict__ B0, const float* __restrict__ B1,
    const float* __restrict__ B2, const float* __restrict__ B3,
    float* __restrict__ out, int batch)
{
  const int tid  = threadIdx.x;
  const int lane = tid & 63;
  const int wv   = __builtin_amdgcn_readfirstlane(tid >> 6); // wave id 0..3, SGPR
  const int b    = blockIdx.x * 4 + wv;
  if (b >= batch) return;

  const int p  = lane >> 2;          // 0..15
  const int q0 = (lane & 3) << 2;    // 0,4,8,12

  // Preload this thread's operand slices into registers (static indices only).
  float  Arow[16];
  float4 Bq[16];
  static_for<16>([&](auto Rc){
    constexpr int r = decltype(Rc)::value;
    if constexpr (r == 0){
      Arow[r] = A0[b*16 + p];
      Bq[r]   = *(const float4*)&B0[b*16 + q0];
    } else if constexpr (r < 4){
      Arow[r] = A1[b*48 + (r-1)*16 + p];
      Bq[r]   = *(const float4*)&B1[b*48 + (r-1)*16 + q0];
    } else if constexpr (r < 9){
      Arow[r] = A2[b*80 + (r-4)*16 + p];
      Bq[r]   = *(const float4*)&B2[b*80 + (r-4)*16 + q0];
    } else {
      Arow[r] = A3[b*112 + (r-9)*16 + p];
      Bq[r]   = *(const float4*)&B3[b*112 + (r-9)*16 + q0];
    }
  });

  float* outb = out + (size_t)b * PB_OUT + (lane << 2);

  static_for<NTILES>([&](auto Tc){
    constexpr int ti   = decltype(Tc)::value;
    constexpr int meta = k_tab.tiles[ti];
    constexpr int ooff = meta & 0xFFFF;
    constexpr int ts   = (meta >> 16) & 0x3FF;
    constexpr int tc   = meta >> 26;
    float4 acc = {0.f, 0.f, 0.f, 0.f};
    static_for<tc>([&](auto Jc){
      constexpr int   j  = decltype(Jc)::value;
      constexpr int   pk = k_tab.tpack[ts + j];
      constexpr float cg = k_tab.tcg[ts + j];
      constexpr int   ar = (pk & 0xFF) >> 4;   // packed A row 0..15
      constexpr int   br = (pk >> 12);         // packed B row 0..15
      const float  ca = cg * Arow[ar];         // cg is an instruction literal
      const float4 bq = Bq[br];
      acc.x = fmaf(ca, bq.x, acc.x);
      acc.y = fmaf(ca, bq.y, acc.y);
      acc.z = fmaf(ca, bq.z, acc.z);
      acc.w = fmaf(ca, bq.w, acc.w);
    });
    *(float4*)(outb + ooff) = acc;             // 1KB/wave, coalesced
  });
}

extern "C" void kernel_launch(void* const* d_in, const int* in_sizes, int n_in,
                              void* d_out, int out_size, void* d_ws, size_t ws_size,
                              hipStream_t stream)
{
  // setup_inputs() dict order is INTERLEAVED: A0,B0,A1,B1,A2,B2,A3,B3
  const float* A0 = (const float*)d_in[0];
  const float* B0 = (const float*)d_in[1];
  const float* A1 = (const float*)d_in[2];
  const float* B1 = (const float*)d_in[3];
  const float* A2 = (const float*)d_in[4];
  const float* B2 = (const float*)d_in[5];
  const float* A3 = (const float*)d_in[6];
  const float* B3 = (const float*)d_in[7];
  float* out = (float*)d_out;

  // A0 is [batch,1,16]; in_sizes are element counts (proven by passing runs).
  const int batch = in_sizes[0] / 16;
  const int grid  = (batch + 3) / 4;   // 4 batch elements per block (1 per wave)

  cg_main<<<grid, 256, 0, stream>>>(A0, A1, A2, A3, B0, B1, B2, B3, out, batch);
}